// Round 8
// baseline (51.825 us; speedup 1.0000x reference)
//
#include <hip/hip_runtime.h>

typedef float  f32x4 __attribute__((ext_vector_type(4)));
typedef short  s16x8 __attribute__((ext_vector_type(8)));
typedef ushort u16x8 __attribute__((ext_vector_type(8)));

constexpr int D  = 128;
constexpr int K  = 512;
constexpr int O  = 256;
constexpr int NT = 256;
constexpr float NL2E = -1.44269504088896340736f;  // -log2(e)

__device__ __forceinline__ ushort f2bf(float f) {
    uint u = __builtin_bit_cast(uint, f);
    return (ushort)((u + 0x7FFFu + ((u >> 16) & 1u)) >> 16);
}
__device__ __forceinline__ float bf2f(ushort h) {
    return __builtin_bit_cast(float, ((uint)h) << 16);
}

// ================= prep: fragment-ordered bf16 operands + fused stats =================
// chunk layout: chunk c holds 64 lanes x 8 bf16 (16B/lane, contiguous 1KB).
// X/C: c = (panel16*4 + q)*64 + lane ; elem = src[panel*16 + (lane&15)][q*32 + (lane>>4)*8 + j]
// W:   c = (kslab32*16 + ot)*64 + lane; elem = w[ot*16 + (lane&15)][kslab*32 + (lane>>4)*8 + j]
__global__ __launch_bounds__(NT)
void rbf_prep(const float* __restrict__ x, const float* __restrict__ cen,
              const float* __restrict__ ls, const float* __restrict__ w,
              ushort* __restrict__ Xh, ushort* __restrict__ Xl,
              ushort* __restrict__ Ch, ushort* __restrict__ Cl,
              ushort* __restrict__ Wf, float* __restrict__ xs2,
              float2* __restrict__ ecs, int nxb, int ncb)
{
    __shared__ float red[4][16];
    const int b = blockIdx.x, t = threadIdx.x, lane = t & 63, wq = t >> 6;

    if (b < nxb + ncb) {
        const bool isX  = b < nxb;
        const int panel = isX ? b : (b - nxb);
        const float* src = isX ? x : cen;
        ushort* dh = isX ? Xh : Ch;
        ushort* dl = isX ? Xl : Cl;
        const int row = panel * 16 + (lane & 15);
        const int col = wq * 32 + (lane >> 4) * 8;
        const float* p = src + (size_t)row * D + col;
        float4 v0 = *(const float4*)p, v1 = *(const float4*)(p + 4);
        float f[8] = {v0.x, v0.y, v0.z, v0.w, v1.x, v1.y, v1.z, v1.w};
        u16x8 h, l;
        float s = 0.f;
#pragma unroll
        for (int j = 0; j < 8; ++j) {
            s = fmaf(f[j], f[j], s);
            ushort hb = f2bf(f[j]);
            h[j] = hb;
            l[j] = f2bf(f[j] - bf2f(hb));
        }
        const size_t c = ((size_t)panel * 4 + wq) * 64 + lane;
        *(u16x8*)&dh[c * 8] = h;
        *(u16x8*)&dl[c * 8] = l;
        s += __shfl_xor(s, 16);
        s += __shfl_xor(s, 32);
        if (lane < 16) red[wq][lane] = s;
        __syncthreads();
        if (t < 16) {
            float sum = red[0][t] + red[1][t] + red[2][t] + red[3][t];
            if (isX) {
                xs2[panel * 16 + t] = sum;
            } else {
                int k = panel * 16 + t;
                float e = __expf(2.0f * ls[k]);
                ecs[k] = make_float2(NL2E * e, NL2E * e * sum);
            }
        }
    } else {
        const int c0 = (b - nxb - ncb) * NT + t;
        const int ln = c0 & 63, ot = (c0 >> 6) & 15, ks = c0 >> 10;
        const int o  = ot * 16 + (ln & 15);
        const int kb = ks * 32 + (ln >> 4) * 8;
        const float* p = w + (size_t)o * K + kb;
        float4 v0 = *(const float4*)p, v1 = *(const float4*)(p + 4);
        u16x8 h;
        h[0] = f2bf(v0.x); h[1] = f2bf(v0.y); h[2] = f2bf(v0.z); h[3] = f2bf(v0.w);
        h[4] = f2bf(v1.x); h[5] = f2bf(v1.y); h[6] = f2bf(v1.z); h[7] = f2bf(v1.w);
        *(u16x8*)&Wf[(size_t)c0 * 8] = h;
    }
}

// ================= stage A: 16-row panel x K-half per block, 4 waves (256 thr) =================
// block b: pan = b>>1 (rows pan*16..+16), h = b&1 (kernels h*256..+256)
// wave wv: owns 64 kernels (2 slabs of 32), full 16x256 partial output
constexpr int PP = 40;   // Ps row stride in ushorts

__global__ __launch_bounds__(NT, 2)   // identical bounds to round-5 main (VGPR 104, no spill)
void rbf_partA(const ushort* __restrict__ Xh, const ushort* __restrict__ Xl,
               const ushort* __restrict__ Ch, const ushort* __restrict__ Cl,
               const ushort* __restrict__ Wf, const float* __restrict__ xs2,
               const float2* __restrict__ ecs,
               float* __restrict__ Pp, float* __restrict__ Lw, int N)
{
    __shared__ ushort Ps[4][16][PP];
    __shared__ float  Acc[16][O + 4];
    __shared__ float  Ls[4][16];

    const int t = threadIdx.x, lane = t & 63, wv = t >> 6;   // wv 0..3
    const int l15 = lane & 15, l4 = lane >> 4;
    const int b = blockIdx.x;
    const int pan = b >> 1, h = b & 1;

    // X fragments (frag-ordered -> base + lane*16B)
    s16x8 xh[4], xl[4];
    {
        const size_t base = ((size_t)pan * 4) * 64 + lane;
#pragma unroll
        for (int q = 0; q < 4; ++q) {
            xh[q] = *(const s16x8*)&Xh[(base + q * 64) * 8];
            xl[q] = *(const s16x8*)&Xl[(base + q * 64) * 8];
        }
    }
    const float xs2v = xs2[pan * 16 + l15];

    f32x4 oacc[16];
#pragma unroll
    for (int i = 0; i < 16; ++i) oacc[i] = (f32x4){0.f, 0.f, 0.f, 0.f};
    float Lp = 0.f;

    const int kw = h * 256 + wv * 64;   // wave's kernel base

#pragma unroll
    for (int s = 0; s < 2; ++s) {
        const int kslab = (kw >> 5) + s;
        const ushort* wbase = &Wf[(((size_t)kslab * 16) * 64 + lane) * 8];

        // GEMM1 (swapped: A=C, B=X) + exp2, two 16-kernel tiles
#pragma unroll
        for (int bt = 0; bt < 2; ++bt) {
            const size_t kt16 = (size_t)(kw >> 4) + s * 2 + bt;
            s16x8 ch[4], cl[4];
#pragma unroll
            for (int q = 0; q < 4; ++q) {
                const size_t cc = ((kt16 * 4 + q) * 64 + lane) * 8;
                ch[q] = *(const s16x8*)&Ch[cc];
                cl[q] = *(const s16x8*)&Cl[cc];
            }
            f32x4 ghh = (f32x4){0.f,0.f,0.f,0.f};
            f32x4 ghl = (f32x4){0.f,0.f,0.f,0.f};
            f32x4 glh = (f32x4){0.f,0.f,0.f,0.f};
#pragma unroll
            for (int q = 0; q < 4; ++q) {
                ghh = __builtin_amdgcn_mfma_f32_16x16x32_bf16(ch[q], xh[q], ghh, 0, 0, 0);
                ghl = __builtin_amdgcn_mfma_f32_16x16x32_bf16(ch[q], xl[q], ghl, 0, 0, 0);
                glh = __builtin_amdgcn_mfma_f32_16x16x32_bf16(cl[q], xh[q], glh, 0, 0, 0);
            }
            f32x4 g = ghh + ghl + glh;

            const int kbase = kw + s * 32 + bt * 16 + l4 * 4;
            float4 e0 = *(const float4*)&ecs[kbase];
            float4 e1 = *(const float4*)&ecs[kbase + 2];
            float ph0 = exp2f(fmaf(e0.x, fmaf(-2.f, g[0], xs2v), e0.y));
            float ph1 = exp2f(fmaf(e0.z, fmaf(-2.f, g[1], xs2v), e0.w));
            float ph2 = exp2f(fmaf(e1.x, fmaf(-2.f, g[2], xs2v), e1.y));
            float ph3 = exp2f(fmaf(e1.z, fmaf(-2.f, g[3], xs2v), e1.w));
            Lp += (ph0 + ph1) + (ph2 + ph3);
            uint p0 = (uint)f2bf(ph0) | ((uint)f2bf(ph1) << 16);
            uint p1 = (uint)f2bf(ph2) | ((uint)f2bf(ph3) << 16);
            *(uint2*)&Ps[wv][l15][bt * 16 + l4 * 4] = make_uint2(p0, p1);
        }

        // wave-private transpose read (same-wave DS order, no barrier) + GEMM2
        s16x8 pa = *(const s16x8*)&Ps[wv][l15][l4 * 8];
#pragma unroll
        for (int ot = 0; ot < 16; ++ot) {
            s16x8 bfr = *(const s16x8*)&wbase[(size_t)ot * 64 * 8];
            oacc[ot] = __builtin_amdgcn_mfma_f32_16x16x32_bf16(pa, bfr, oacc[ot], 0, 0, 0);
        }
    }

    // per-wave row sums (over its 64 kernels)
    {
        float v = Lp;
        v += __shfl_xor(v, 16);
        v += __shfl_xor(v, 32);
        if (lane < 16) Ls[wv][lane] = v;
    }

    // combine 4 wave partials: rotation schedule, all waves active
#pragma unroll
    for (int st = 0; st < 4; ++st) {
        const int oq = (wv + st) & 3;            // quarter of ot-tiles (64 cols)
        if (st == 0) {
#pragma unroll
            for (int j = 0; j < 4; ++j) {
                const int ot = oq * 4 + j;
#pragma unroll
                for (int r = 0; r < 4; ++r)
                    Acc[l4 * 4 + r][ot * 16 + l15] = oacc[ot][r];
            }
        } else {
#pragma unroll
            for (int j = 0; j < 4; ++j) {
                const int ot = oq * 4 + j;
#pragma unroll
                for (int r = 0; r < 4; ++r)
                    Acc[l4 * 4 + r][ot * 16 + l15] += oacc[ot][r];
            }
        }
        __syncthreads();
    }

    // store partial output (fp32) + partial row sums
    {
        const int n2 = t >> 4;           // 0..15
        const int c0 = (t & 15) * 16;    // 0..240
        float* dst = &Pp[((size_t)h * N + (size_t)pan * 16 + n2) * O + c0];
        const float* src = &Acc[n2][c0];
#pragma unroll
        for (int j = 0; j < 4; ++j)
            *(float4*)(dst + j * 4) = *(const float4*)(src + j * 4);
    }
    if (t < 16) {
        Lw[(size_t)h * N + pan * 16 + t] = Ls[0][t] + Ls[1][t] + Ls[2][t] + Ls[3][t];
    }
}

// ================= stage B: combine K-halves + normalize =================
__global__ __launch_bounds__(NT)
void rbf_reduce(const float* __restrict__ Pp, const float* __restrict__ Lw,
                float* __restrict__ out, int N)
{
    const int i = blockIdx.x * NT + threadIdx.x;    // float4 index, N*O/4 total
    const int n = i >> 6;                           // row (O/4 = 64 float4/row)
    const float inv = 1.0f / (Lw[n] + Lw[N + n] + 1e-9f);
    const float4 a = ((const float4*)Pp)[i];
    const float4 c = ((const float4*)Pp)[(size_t)N * (O / 4) + i];
    float4 o;
    o.x = (a.x + c.x) * inv;
    o.y = (a.y + c.y) * inv;
    o.z = (a.z + c.z) * inv;
    o.w = (a.w + c.w) * inv;
    ((float4*)out)[i] = o;
}

// ================= fallback (round-4 kernel, known-pass, no ws) =================
__global__ __launch_bounds__(NT, 2)
void rbf_fb(const float* __restrict__ x, const float* __restrict__ cen,
            const float* __restrict__ ls, const float* __restrict__ w,
            float* __restrict__ out)
{
    __shared__ ushort Ps2[2][4][16][PP];
    __shared__ float  Acc2[2][16][O + 4];
    __shared__ float  Ls2[4][16];
    const int t = threadIdx.x, lane = t & 63, wv = t >> 6;
    const int l15 = lane & 15, l4 = lane >> 4;
    const int nb = blockIdx.x * 16;

    s16x8 xh[4], xl[4];
    float sx = 0.f;
    {
        const float* xr = x + (size_t)(nb + l15) * D;
#pragma unroll
        for (int q = 0; q < 4; ++q) {
            float4 v0 = *(const float4*)(xr + q * 32 + l4 * 8);
            float4 v1 = *(const float4*)(xr + q * 32 + l4 * 8 + 4);
            float f[8] = {v0.x, v0.y, v0.z, v0.w, v1.x, v1.y, v1.z, v1.w};
            s16x8 hh, lo;
#pragma unroll
            for (int j = 0; j < 8; ++j) {
                sx = fmaf(f[j], f[j], sx);
                ushort hb = f2bf(f[j]);
                hh[j] = (short)hb; lo[j] = (short)f2bf(f[j] - bf2f(hb));
            }
            xh[q] = hh; xl[q] = lo;
        }
    }
    sx += __shfl_xor(sx, 16); sx += __shfl_xor(sx, 32);
    float xs2v[4];
#pragma unroll
    for (int r = 0; r < 4; ++r) xs2v[r] = __shfl(sx, l4 * 4 + r);

    f32x4 oacc[16];
#pragma unroll
    for (int ot = 0; ot < 16; ++ot) oacc[ot] = (f32x4){0.f,0.f,0.f,0.f};
    float Lp[4] = {0.f,0.f,0.f,0.f};
    const int kq = wv * (K / 4);

#pragma unroll
    for (int s = 0; s < 4; ++s) {
        const int k0 = kq + s * 32;
#pragma unroll
        for (int bt = 0; bt < 2; ++bt) {
            const int kk = k0 + bt * 16 + l15;
            const float* cr = cen + (size_t)kk * D;
            s16x8 ch[4], cl[4];
            float sc = 0.f;
#pragma unroll
            for (int q = 0; q < 4; ++q) {
                float4 v0 = *(const float4*)(cr + q * 32 + l4 * 8);
                float4 v1 = *(const float4*)(cr + q * 32 + l4 * 8 + 4);
                float f[8] = {v0.x, v0.y, v0.z, v0.w, v1.x, v1.y, v1.z, v1.w};
                s16x8 hh, lo;
#pragma unroll
                for (int j = 0; j < 8; ++j) {
                    sc = fmaf(f[j], f[j], sc);
                    ushort hb = f2bf(f[j]);
                    hh[j] = (short)hb; lo[j] = (short)f2bf(f[j] - bf2f(hb));
                }
                ch[q] = hh; cl[q] = lo;
            }
            sc += __shfl_xor(sc, 16); sc += __shfl_xor(sc, 32);
            float es_ = __expf(2.0f * ls[kk]);
            f32x4 ghh={0,0,0,0}, ghl={0,0,0,0}, glh={0,0,0,0};
#pragma unroll
            for (int q = 0; q < 4; ++q) {
                ghh = __builtin_amdgcn_mfma_f32_16x16x32_bf16(xh[q], ch[q], ghh, 0,0,0);
                ghl = __builtin_amdgcn_mfma_f32_16x16x32_bf16(xh[q], cl[q], ghl, 0,0,0);
                glh = __builtin_amdgcn_mfma_f32_16x16x32_bf16(xl[q], ch[q], glh, 0,0,0);
            }
            f32x4 gg = ghh + ghl + glh;
#pragma unroll
            for (int r = 0; r < 4; ++r) {
                float r2 = xs2v[r] + sc - 2.0f * gg[r];
                float ph = __expf(-es_ * r2);
                Lp[r] += ph;
                Ps2[s & 1][wv][l4 * 4 + r][bt * 16 + l15] = f2bf(ph);
            }
        }
        s16x8 pa = *(const s16x8*)&Ps2[s & 1][wv][l15][l4 * 8];
#pragma unroll
        for (int ot = 0; ot < 16; ++ot) {
            const float* wr = w + (size_t)(ot * 16 + l15) * K + k0;
            float4 v0 = *(const float4*)(wr + l4 * 8);
            float4 v1 = *(const float4*)(wr + l4 * 8 + 4);
            s16x8 bb;
            bb[0]=(short)f2bf(v0.x); bb[1]=(short)f2bf(v0.y); bb[2]=(short)f2bf(v0.z); bb[3]=(short)f2bf(v0.w);
            bb[4]=(short)f2bf(v1.x); bb[5]=(short)f2bf(v1.y); bb[6]=(short)f2bf(v1.z); bb[7]=(short)f2bf(v1.w);
            oacc[ot] = __builtin_amdgcn_mfma_f32_16x16x32_bf16(pa, bb, oacc[ot], 0,0,0);
        }
    }
#pragma unroll
    for (int r = 0; r < 4; ++r) {
        float v = Lp[r];
        v += __shfl_xor(v, 1); v += __shfl_xor(v, 2);
        v += __shfl_xor(v, 4); v += __shfl_xor(v, 8);
        if (l15 == 0) Ls2[wv][l4 * 4 + r] = v;
    }
    if (wv < 2) {
#pragma unroll
        for (int ot = 0; ot < 16; ++ot)
#pragma unroll
            for (int r = 0; r < 4; ++r)
                Acc2[wv][l4 * 4 + r][ot * 16 + l15] = oacc[ot][r];
    }
    __syncthreads();
    if (wv >= 2) {
#pragma unroll
        for (int ot = 0; ot < 16; ++ot)
#pragma unroll
            for (int r = 0; r < 4; ++r)
                Acc2[wv - 2][l4 * 4 + r][ot * 16 + l15] += oacc[ot][r];
    }
    __syncthreads();
#pragma unroll
    for (int rr = 0; rr < 4; ++rr) {
        const int n = wv * 4 + rr;
        float inv = 1.0f / (Ls2[0][n] + Ls2[1][n] + Ls2[2][n] + Ls2[3][n] + 1e-9f);
        float4 a0 = *(const float4*)&Acc2[0][n][lane * 4];
        float4 a1 = *(const float4*)&Acc2[1][n][lane * 4];
        float4 o4;
        o4.x = (a0.x + a1.x) * inv; o4.y = (a0.y + a1.y) * inv;
        o4.z = (a0.z + a1.z) * inv; o4.w = (a0.w + a1.w) * inv;
        *(float4*)&out[(size_t)(nb + n) * O + lane * 4] = o4;
    }
}

extern "C" void kernel_launch(void* const* d_in, const int* in_sizes, int n_in,
                              void* d_out, int out_size, void* d_ws, size_t ws_size,
                              hipStream_t stream) {
    const float* x   = (const float*)d_in[0];  // N x 128
    const float* cen = (const float*)d_in[1];  // 512 x 128
    const float* ls  = (const float*)d_in[2];  // 512
    const float* w   = (const float*)d_in[3];  // 256 x 512
    float* out = (float*)d_out;                // N x 256
    const int N = in_sizes[0] / D;             // 8192

    size_t oXh = 0;
    size_t oXl = oXh + (size_t)N * D * 2;
    size_t oCh = oXl + (size_t)N * D * 2;
    size_t oCl = oCh + (size_t)K * D * 2;
    size_t oWf = oCl + (size_t)K * D * 2;
    size_t oxs = oWf + (size_t)O * K * 2;
    size_t oec = oxs + (size_t)N * 4;
    size_t oPp = oec + (size_t)K * 8;
    size_t oLw = oPp + (size_t)2 * N * O * 4;
    size_t need = oLw + (size_t)2 * N * 4;

    if (ws_size < need || (N % 16) != 0) {
        dim3 grid(N / 16), block(NT);
        hipLaunchKernelGGL(rbf_fb, grid, block, 0, stream, x, cen, ls, w, out);
        return;
    }

    char* ws = (char*)d_ws;
    ushort* Xh = (ushort*)(ws + oXh);
    ushort* Xl = (ushort*)(ws + oXl);
    ushort* Ch = (ushort*)(ws + oCh);
    ushort* Cl = (ushort*)(ws + oCl);
    ushort* Wf = (ushort*)(ws + oWf);
    float*  xs2 = (float*)(ws + oxs);
    float2* ecs = (float2*)(ws + oec);
    float*  Pp  = (float*)(ws + oPp);
    float*  Lw  = (float*)(ws + oLw);

    const int nxb = N / 16;                    // X panels
    const int ncb = K / 16;                    // C panels
    const int nwb = (O * K / 8) / NT;          // W blocks
    dim3 pgrid(nxb + ncb + nwb), pblock(NT);
    hipLaunchKernelGGL(rbf_prep, pgrid, pblock, 0, stream,
                       x, cen, ls, w, Xh, Xl, Ch, Cl, Wf, xs2, ecs, nxb, ncb);

    dim3 agrid((N / 16) * 2), ablock(NT);
    hipLaunchKernelGGL(rbf_partA, agrid, ablock, 0, stream,
                       Xh, Xl, Ch, Cl, Wf, xs2, ecs, Pp, Lw, N);

    dim3 rgrid((N * O / 4) / NT), rblock(NT);
    hipLaunchKernelGGL(rbf_reduce, rgrid, rblock, 0, stream, Pp, Lw, out, N);
}

// Round 9
// 38.951 us; speedup vs baseline: 1.3305x; 1.3305x over previous
//
#include <hip/hip_runtime.h>

typedef float  f32x4 __attribute__((ext_vector_type(4)));
typedef short  s16x8 __attribute__((ext_vector_type(8)));
typedef ushort u16x8 __attribute__((ext_vector_type(8)));

constexpr int D  = 128;
constexpr int K  = 512;
constexpr int O  = 256;
constexpr int NT = 256;
constexpr float NL2E = -1.44269504088896340736f;  // -log2(e)

__device__ __forceinline__ ushort f2bf(float f) {
    uint u = __builtin_bit_cast(uint, f);
    return (ushort)((u + 0x7FFFu + ((u >> 16) & 1u)) >> 16);
}
__device__ __forceinline__ float bf2f(ushort h) {
    return __builtin_bit_cast(float, ((uint)h) << 16);
}

// ================= prep: fragment-ordered bf16 operands + fused stats =================
// chunk layout: chunk c holds 64 lanes x 8 bf16 (16B/lane, contiguous 1KB).
// X/C: c = (panel16*4 + q)*64 + lane ; elem = src[panel*16 + (lane&15)][q*32 + (lane>>4)*8 + j]
// W:   c = (kslab32*16 + ot)*64 + lane; elem = w[ot*16 + (lane&15)][kslab*32 + (lane>>4)*8 + j]
__global__ __launch_bounds__(NT)
void rbf_prep(const float* __restrict__ x, const float* __restrict__ cen,
              const float* __restrict__ ls, const float* __restrict__ w,
              ushort* __restrict__ Xh, ushort* __restrict__ Xl,
              ushort* __restrict__ Ch, ushort* __restrict__ Cl,
              ushort* __restrict__ Wf, float* __restrict__ xs2,
              float2* __restrict__ ecs, int nxb, int ncb)
{
    __shared__ float red[4][16];
    const int b = blockIdx.x, t = threadIdx.x, lane = t & 63, wq = t >> 6;

    if (b < nxb + ncb) {
        const bool isX  = b < nxb;
        const int panel = isX ? b : (b - nxb);
        const float* src = isX ? x : cen;
        ushort* dh = isX ? Xh : Ch;
        ushort* dl = isX ? Xl : Cl;
        const int row = panel * 16 + (lane & 15);
        const int col = wq * 32 + (lane >> 4) * 8;
        const float* p = src + (size_t)row * D + col;
        float4 v0 = *(const float4*)p, v1 = *(const float4*)(p + 4);
        float f[8] = {v0.x, v0.y, v0.z, v0.w, v1.x, v1.y, v1.z, v1.w};
        u16x8 h, l;
        float s = 0.f;
#pragma unroll
        for (int j = 0; j < 8; ++j) {
            s = fmaf(f[j], f[j], s);
            ushort hb = f2bf(f[j]);
            h[j] = hb;
            l[j] = f2bf(f[j] - bf2f(hb));
        }
        const size_t c = ((size_t)panel * 4 + wq) * 64 + lane;
        *(u16x8*)&dh[c * 8] = h;
        *(u16x8*)&dl[c * 8] = l;
        s += __shfl_xor(s, 16);
        s += __shfl_xor(s, 32);
        if (lane < 16) red[wq][lane] = s;
        __syncthreads();
        if (t < 16) {
            float sum = red[0][t] + red[1][t] + red[2][t] + red[3][t];
            if (isX) {
                xs2[panel * 16 + t] = sum;
            } else {
                int k = panel * 16 + t;
                float e = __expf(2.0f * ls[k]);
                ecs[k] = make_float2(NL2E * e, NL2E * e * sum);
            }
        }
    } else {
        const int c0 = (b - nxb - ncb) * NT + t;
        const int ln = c0 & 63, ot = (c0 >> 6) & 15, ks = c0 >> 10;
        const int o  = ot * 16 + (ln & 15);
        const int kb = ks * 32 + (ln >> 4) * 8;
        const float* p = w + (size_t)o * K + kb;
        float4 v0 = *(const float4*)p, v1 = *(const float4*)(p + 4);
        u16x8 h;
        h[0] = f2bf(v0.x); h[1] = f2bf(v0.y); h[2] = f2bf(v0.z); h[3] = f2bf(v0.w);
        h[4] = f2bf(v1.x); h[5] = f2bf(v1.y); h[6] = f2bf(v1.z); h[7] = f2bf(v1.w);
        *(u16x8*)&Wf[(size_t)c0 * 8] = h;
    }
}

// ================= stage A: 16-row panel x K-half per block, 4 waves (256 thr) =================
// block b: pan = b>>1 (rows pan*16..+16), h = b&1 (kernels h*256..+256)
// wave wv: owns 64 kernels (2 slabs of 32), full 16x256 partial output
// NOTE: combine uses ONLY compile-time indices into oacc (rule #20: runtime
// indexing demotes the whole array to scratch — this was rounds 6-8's bug).
constexpr int PP = 40;   // Ps row stride in ushorts

__global__ __launch_bounds__(NT, 2)
void rbf_partA(const ushort* __restrict__ Xh, const ushort* __restrict__ Xl,
               const ushort* __restrict__ Ch, const ushort* __restrict__ Cl,
               const ushort* __restrict__ Wf, const float* __restrict__ xs2,
               const float2* __restrict__ ecs,
               float* __restrict__ Pp, float* __restrict__ Lw, int N)
{
    __shared__ ushort Ps[4][16][PP];
    __shared__ float  Acc[2][16][O + 4];
    __shared__ float  Ls[4][16];

    const int t = threadIdx.x, lane = t & 63, wv = t >> 6;   // wv 0..3
    const int l15 = lane & 15, l4 = lane >> 4;
    const int b = blockIdx.x;
    const int pan = b >> 1, h = b & 1;

    // X fragments (frag-ordered -> base + lane*16B)
    s16x8 xh[4], xl[4];
    {
        const size_t base = ((size_t)pan * 4) * 64 + lane;
#pragma unroll
        for (int q = 0; q < 4; ++q) {
            xh[q] = *(const s16x8*)&Xh[(base + q * 64) * 8];
            xl[q] = *(const s16x8*)&Xl[(base + q * 64) * 8];
        }
    }
    const float xs2v = xs2[pan * 16 + l15];

    f32x4 oacc[16];
#pragma unroll
    for (int i = 0; i < 16; ++i) oacc[i] = (f32x4){0.f, 0.f, 0.f, 0.f};
    float Lp = 0.f;

    const int kw = h * 256 + wv * 64;   // wave's kernel base

#pragma unroll
    for (int s = 0; s < 2; ++s) {
        const int kslab = (kw >> 5) + s;
        const ushort* wbase = &Wf[(((size_t)kslab * 16) * 64 + lane) * 8];

        // GEMM1 (swapped: A=C, B=X) + exp2, two 16-kernel tiles
#pragma unroll
        for (int bt = 0; bt < 2; ++bt) {
            const size_t kt16 = (size_t)(kw >> 4) + s * 2 + bt;
            s16x8 ch[4], cl[4];
#pragma unroll
            for (int q = 0; q < 4; ++q) {
                const size_t cc = ((kt16 * 4 + q) * 64 + lane) * 8;
                ch[q] = *(const s16x8*)&Ch[cc];
                cl[q] = *(const s16x8*)&Cl[cc];
            }
            f32x4 ghh = (f32x4){0.f,0.f,0.f,0.f};
            f32x4 ghl = (f32x4){0.f,0.f,0.f,0.f};
            f32x4 glh = (f32x4){0.f,0.f,0.f,0.f};
#pragma unroll
            for (int q = 0; q < 4; ++q) {
                ghh = __builtin_amdgcn_mfma_f32_16x16x32_bf16(ch[q], xh[q], ghh, 0, 0, 0);
                ghl = __builtin_amdgcn_mfma_f32_16x16x32_bf16(ch[q], xl[q], ghl, 0, 0, 0);
                glh = __builtin_amdgcn_mfma_f32_16x16x32_bf16(cl[q], xh[q], glh, 0, 0, 0);
            }
            f32x4 g = ghh + ghl + glh;

            const int kbase = kw + s * 32 + bt * 16 + l4 * 4;
            float4 e0 = *(const float4*)&ecs[kbase];
            float4 e1 = *(const float4*)&ecs[kbase + 2];
            float ph0 = exp2f(fmaf(e0.x, fmaf(-2.f, g[0], xs2v), e0.y));
            float ph1 = exp2f(fmaf(e0.z, fmaf(-2.f, g[1], xs2v), e0.w));
            float ph2 = exp2f(fmaf(e1.x, fmaf(-2.f, g[2], xs2v), e1.y));
            float ph3 = exp2f(fmaf(e1.z, fmaf(-2.f, g[3], xs2v), e1.w));
            Lp += (ph0 + ph1) + (ph2 + ph3);
            uint p0 = (uint)f2bf(ph0) | ((uint)f2bf(ph1) << 16);
            uint p1 = (uint)f2bf(ph2) | ((uint)f2bf(ph3) << 16);
            *(uint2*)&Ps[wv][l15][bt * 16 + l4 * 4] = make_uint2(p0, p1);
        }

        // wave-private transpose read (same-wave DS order, no barrier) + GEMM2
        s16x8 pa = *(const s16x8*)&Ps[wv][l15][l4 * 8];
#pragma unroll
        for (int ot = 0; ot < 16; ++ot) {
            s16x8 bfr = *(const s16x8*)&wbase[(size_t)ot * 64 * 8];
            oacc[ot] = __builtin_amdgcn_mfma_f32_16x16x32_bf16(pa, bfr, oacc[ot], 0, 0, 0);
        }
    }

    // per-wave row sums (over its 64 kernels)
    {
        float v = Lp;
        v += __shfl_xor(v, 16);
        v += __shfl_xor(v, 32);
        if (lane < 16) Ls[wv][lane] = v;
    }

    // ---- combine 4 wave partials: STATIC oacc indices only ----
    if (wv < 2) {
#pragma unroll
        for (int ot = 0; ot < 16; ++ot)
#pragma unroll
            for (int r = 0; r < 4; ++r)
                Acc[wv][l4 * 4 + r][ot * 16 + l15] = oacc[ot][r];
    }
    __syncthreads();
    if (wv >= 2) {
#pragma unroll
        for (int ot = 0; ot < 16; ++ot)
#pragma unroll
            for (int r = 0; r < 4; ++r)
                Acc[wv - 2][l4 * 4 + r][ot * 16 + l15] += oacc[ot][r];
    }
    __syncthreads();

    // store partial output (fp32, Acc[0]+Acc[1]) + partial row sums
    {
        const int n2 = t >> 4;           // 0..15
        const int c0 = (t & 15) * 16;    // 0..240
        float* dst = &Pp[((size_t)h * N + (size_t)pan * 16 + n2) * O + c0];
#pragma unroll
        for (int j = 0; j < 4; ++j) {
            float4 a = *(const float4*)&Acc[0][n2][c0 + j * 4];
            float4 c = *(const float4*)&Acc[1][n2][c0 + j * 4];
            float4 o;
            o.x = a.x + c.x; o.y = a.y + c.y;
            o.z = a.z + c.z; o.w = a.w + c.w;
            *(float4*)(dst + j * 4) = o;
        }
    }
    if (t < 16) {
        Lw[(size_t)h * N + pan * 16 + t] = Ls[0][t] + Ls[1][t] + Ls[2][t] + Ls[3][t];
    }
}

// ================= stage B: combine K-halves + normalize =================
__global__ __launch_bounds__(NT)
void rbf_reduce(const float* __restrict__ Pp, const float* __restrict__ Lw,
                float* __restrict__ out, int N)
{
    const int i = blockIdx.x * NT + threadIdx.x;    // float4 index, N*O/4 total
    const int n = i >> 6;                           // row (O/4 = 64 float4/row)
    const float inv = 1.0f / (Lw[n] + Lw[N + n] + 1e-9f);
    const float4 a = ((const float4*)Pp)[i];
    const float4 c = ((const float4*)Pp)[(size_t)N * (O / 4) + i];
    float4 o;
    o.x = (a.x + c.x) * inv;
    o.y = (a.y + c.y) * inv;
    o.z = (a.z + c.z) * inv;
    o.w = (a.w + c.w) * inv;
    ((float4*)out)[i] = o;
}

// ================= fallback (round-4 kernel, known-pass, no ws) =================
__global__ __launch_bounds__(NT, 2)
void rbf_fb(const float* __restrict__ x, const float* __restrict__ cen,
            const float* __restrict__ ls, const float* __restrict__ w,
            float* __restrict__ out)
{
    __shared__ ushort Ps2[2][4][16][PP];
    __shared__ float  Acc2[2][16][O + 4];
    __shared__ float  Ls2[4][16];
    const int t = threadIdx.x, lane = t & 63, wv = t >> 6;
    const int l15 = lane & 15, l4 = lane >> 4;
    const int nb = blockIdx.x * 16;

    s16x8 xh[4], xl[4];
    float sx = 0.f;
    {
        const float* xr = x + (size_t)(nb + l15) * D;
#pragma unroll
        for (int q = 0; q < 4; ++q) {
            float4 v0 = *(const float4*)(xr + q * 32 + l4 * 8);
            float4 v1 = *(const float4*)(xr + q * 32 + l4 * 8 + 4);
            float f[8] = {v0.x, v0.y, v0.z, v0.w, v1.x, v1.y, v1.z, v1.w};
            s16x8 hh, lo;
#pragma unroll
            for (int j = 0; j < 8; ++j) {
                sx = fmaf(f[j], f[j], sx);
                ushort hb = f2bf(f[j]);
                hh[j] = (short)hb; lo[j] = (short)f2bf(f[j] - bf2f(hb));
            }
            xh[q] = hh; xl[q] = lo;
        }
    }
    sx += __shfl_xor(sx, 16); sx += __shfl_xor(sx, 32);
    float xs2v[4];
#pragma unroll
    for (int r = 0; r < 4; ++r) xs2v[r] = __shfl(sx, l4 * 4 + r);

    f32x4 oacc[16];
#pragma unroll
    for (int ot = 0; ot < 16; ++ot) oacc[ot] = (f32x4){0.f,0.f,0.f,0.f};
    float Lp[4] = {0.f,0.f,0.f,0.f};
    const int kq = wv * (K / 4);

#pragma unroll
    for (int s = 0; s < 4; ++s) {
        const int k0 = kq + s * 32;
#pragma unroll
        for (int bt = 0; bt < 2; ++bt) {
            const int kk = k0 + bt * 16 + l15;
            const float* cr = cen + (size_t)kk * D;
            s16x8 ch[4], cl[4];
            float sc = 0.f;
#pragma unroll
            for (int q = 0; q < 4; ++q) {
                float4 v0 = *(const float4*)(cr + q * 32 + l4 * 8);
                float4 v1 = *(const float4*)(cr + q * 32 + l4 * 8 + 4);
                float f[8] = {v0.x, v0.y, v0.z, v0.w, v1.x, v1.y, v1.z, v1.w};
                s16x8 hh, lo;
#pragma unroll
                for (int j = 0; j < 8; ++j) {
                    sc = fmaf(f[j], f[j], sc);
                    ushort hb = f2bf(f[j]);
                    hh[j] = (short)hb; lo[j] = (short)f2bf(f[j] - bf2f(hb));
                }
                ch[q] = hh; cl[q] = lo;
            }
            sc += __shfl_xor(sc, 16); sc += __shfl_xor(sc, 32);
            float es_ = __expf(2.0f * ls[kk]);
            f32x4 ghh={0,0,0,0}, ghl={0,0,0,0}, glh={0,0,0,0};
#pragma unroll
            for (int q = 0; q < 4; ++q) {
                ghh = __builtin_amdgcn_mfma_f32_16x16x32_bf16(xh[q], ch[q], ghh, 0,0,0);
                ghl = __builtin_amdgcn_mfma_f32_16x16x32_bf16(xh[q], cl[q], ghl, 0,0,0);
                glh = __builtin_amdgcn_mfma_f32_16x16x32_bf16(xl[q], ch[q], glh, 0,0,0);
            }
            f32x4 gg = ghh + ghl + glh;
#pragma unroll
            for (int r = 0; r < 4; ++r) {
                float r2 = xs2v[r] + sc - 2.0f * gg[r];
                float ph = __expf(-es_ * r2);
                Lp[r] += ph;
                Ps2[s & 1][wv][l4 * 4 + r][bt * 16 + l15] = f2bf(ph);
            }
        }
        s16x8 pa = *(const s16x8*)&Ps2[s & 1][wv][l15][l4 * 8];
#pragma unroll
        for (int ot = 0; ot < 16; ++ot) {
            const float* wr = w + (size_t)(ot * 16 + l15) * K + k0;
            float4 v0 = *(const float4*)(wr + l4 * 8);
            float4 v1 = *(const float4*)(wr + l4 * 8 + 4);
            s16x8 bb;
            bb[0]=(short)f2bf(v0.x); bb[1]=(short)f2bf(v0.y); bb[2]=(short)f2bf(v0.z); bb[3]=(short)f2bf(v0.w);
            bb[4]=(short)f2bf(v1.x); bb[5]=(short)f2bf(v1.y); bb[6]=(short)f2bf(v1.z); bb[7]=(short)f2bf(v1.w);
            oacc[ot] = __builtin_amdgcn_mfma_f32_16x16x32_bf16(pa, bb, oacc[ot], 0,0,0);
        }
    }
#pragma unroll
    for (int r = 0; r < 4; ++r) {
        float v = Lp[r];
        v += __shfl_xor(v, 1); v += __shfl_xor(v, 2);
        v += __shfl_xor(v, 4); v += __shfl_xor(v, 8);
        if (l15 == 0) Ls2[wv][l4 * 4 + r] = v;
    }
    if (wv < 2) {
#pragma unroll
        for (int ot = 0; ot < 16; ++ot)
#pragma unroll
            for (int r = 0; r < 4; ++r)
                Acc2[wv][l4 * 4 + r][ot * 16 + l15] = oacc[ot][r];
    }
    __syncthreads();
    if (wv >= 2) {
#pragma unroll
        for (int ot = 0; ot < 16; ++ot)
#pragma unroll
            for (int r = 0; r < 4; ++r)
                Acc2[wv - 2][l4 * 4 + r][ot * 16 + l15] += oacc[ot][r];
    }
    __syncthreads();
#pragma unroll
    for (int rr = 0; rr < 4; ++rr) {
        const int n = wv * 4 + rr;
        float inv = 1.0f / (Ls2[0][n] + Ls2[1][n] + Ls2[2][n] + Ls2[3][n] + 1e-9f);
        float4 a0 = *(const float4*)&Acc2[0][n][lane * 4];
        float4 a1 = *(const float4*)&Acc2[1][n][lane * 4];
        float4 o4;
        o4.x = (a0.x + a1.x) * inv; o4.y = (a0.y + a1.y) * inv;
        o4.z = (a0.z + a1.z) * inv; o4.w = (a0.w + a1.w) * inv;
        *(float4*)&out[(size_t)(nb + n) * O + lane * 4] = o4;
    }
}

extern "C" void kernel_launch(void* const* d_in, const int* in_sizes, int n_in,
                              void* d_out, int out_size, void* d_ws, size_t ws_size,
                              hipStream_t stream) {
    const float* x   = (const float*)d_in[0];  // N x 128
    const float* cen = (const float*)d_in[1];  // 512 x 128
    const float* ls  = (const float*)d_in[2];  // 512
    const float* w   = (const float*)d_in[3];  // 256 x 512
    float* out = (float*)d_out;                // N x 256
    const int N = in_sizes[0] / D;             // 8192

    size_t oXh = 0;
    size_t oXl = oXh + (size_t)N * D * 2;
    size_t oCh = oXl + (size_t)N * D * 2;
    size_t oCl = oCh + (size_t)K * D * 2;
    size_t oWf = oCl + (size_t)K * D * 2;
    size_t oxs = oWf + (size_t)O * K * 2;
    size_t oec = oxs + (size_t)N * 4;
    size_t oPp = oec + (size_t)K * 8;
    size_t oLw = oPp + (size_t)2 * N * O * 4;
    size_t need = oLw + (size_t)2 * N * 4;

    if (ws_size < need || (N % 16) != 0) {
        dim3 grid(N / 16), block(NT);
        hipLaunchKernelGGL(rbf_fb, grid, block, 0, stream, x, cen, ls, w, out);
        return;
    }

    char* ws = (char*)d_ws;
    ushort* Xh = (ushort*)(ws + oXh);
    ushort* Xl = (ushort*)(ws + oXl);
    ushort* Ch = (ushort*)(ws + oCh);
    ushort* Cl = (ushort*)(ws + oCl);
    ushort* Wf = (ushort*)(ws + oWf);
    float*  xs2 = (float*)(ws + oxs);
    float2* ecs = (float2*)(ws + oec);
    float*  Pp  = (float*)(ws + oPp);
    float*  Lw  = (float*)(ws + oLw);

    const int nxb = N / 16;                    // X panels
    const int ncb = K / 16;                    // C panels
    const int nwb = (O * K / 8) / NT;          // W blocks
    dim3 pgrid(nxb + ncb + nwb), pblock(NT);
    hipLaunchKernelGGL(rbf_prep, pgrid, pblock, 0, stream,
                       x, cen, ls, w, Xh, Xl, Ch, Cl, Wf, xs2, ecs, nxb, ncb);

    dim3 agrid((N / 16) * 2), ablock(NT);
    hipLaunchKernelGGL(rbf_partA, agrid, ablock, 0, stream,
                       Xh, Xl, Ch, Cl, Wf, xs2, ecs, Pp, Lw, N);

    dim3 rgrid((N * O / 4) / NT), rblock(NT);
    hipLaunchKernelGGL(rbf_reduce, rgrid, rblock, 0, stream, Pp, Lw, out, N);
}

// Round 10
// 27.437 us; speedup vs baseline: 1.8889x; 1.4197x over previous
//
#include <hip/hip_runtime.h>

typedef float  f32x4 __attribute__((ext_vector_type(4)));
typedef short  s16x8 __attribute__((ext_vector_type(8)));
typedef ushort u16x8 __attribute__((ext_vector_type(8)));

constexpr int D  = 128;
constexpr int K  = 512;
constexpr int O  = 256;
constexpr int NT = 256;
constexpr float NL2E = -1.44269504088896340736f;  // -log2(e)

__device__ __forceinline__ ushort f2bf(float f) {
    uint u = __builtin_bit_cast(uint, f);
    return (ushort)((u + 0x7FFFu + ((u >> 16) & 1u)) >> 16);
}
__device__ __forceinline__ float bf2f(ushort h) {
    return __builtin_bit_cast(float, ((uint)h) << 16);
}

// ================= prep: fragment-ordered bf16 operands + fused stats =================
// chunk layout: chunk c holds 64 lanes x 8 bf16 (16B/lane, contiguous 1KB).
// X/C: c = (panel16*4 + q)*64 + lane ; elem = src[panel*16 + (lane&15)][q*32 + (lane>>4)*8 + j]
// W:   c = (kslab32*16 + ot)*64 + lane; elem = w[ot*16 + (lane&15)][kslab*32 + (lane>>4)*8 + j]
__global__ __launch_bounds__(NT)
void rbf_prep(const float* __restrict__ x, const float* __restrict__ cen,
              const float* __restrict__ ls, const float* __restrict__ w,
              ushort* __restrict__ Xh, ushort* __restrict__ Xl,
              ushort* __restrict__ Ch, ushort* __restrict__ Cl,
              ushort* __restrict__ Wf, float* __restrict__ xs2,
              float2* __restrict__ ecs, int nxb, int ncb)
{
    __shared__ float red[4][16];
    const int b = blockIdx.x, t = threadIdx.x, lane = t & 63, wq = t >> 6;

    if (b < nxb + ncb) {
        const bool isX  = b < nxb;
        const int panel = isX ? b : (b - nxb);
        const float* src = isX ? x : cen;
        ushort* dh = isX ? Xh : Ch;
        ushort* dl = isX ? Xl : Cl;
        const int row = panel * 16 + (lane & 15);
        const int col = wq * 32 + (lane >> 4) * 8;
        const float* p = src + (size_t)row * D + col;
        float4 v0 = *(const float4*)p, v1 = *(const float4*)(p + 4);
        float f[8] = {v0.x, v0.y, v0.z, v0.w, v1.x, v1.y, v1.z, v1.w};
        u16x8 h, l;
        float s = 0.f;
#pragma unroll
        for (int j = 0; j < 8; ++j) {
            s = fmaf(f[j], f[j], s);
            ushort hb = f2bf(f[j]);
            h[j] = hb;
            l[j] = f2bf(f[j] - bf2f(hb));
        }
        const size_t c = ((size_t)panel * 4 + wq) * 64 + lane;
        *(u16x8*)&dh[c * 8] = h;
        *(u16x8*)&dl[c * 8] = l;
        s += __shfl_xor(s, 16);
        s += __shfl_xor(s, 32);
        if (lane < 16) red[wq][lane] = s;
        __syncthreads();
        if (t < 16) {
            float sum = red[0][t] + red[1][t] + red[2][t] + red[3][t];
            if (isX) {
                xs2[panel * 16 + t] = sum;
            } else {
                int k = panel * 16 + t;
                float e = __expf(2.0f * ls[k]);
                ecs[k] = make_float2(NL2E * e, NL2E * e * sum);
            }
        }
    } else {
        const int c0 = (b - nxb - ncb) * NT + t;
        const int ln = c0 & 63, ot = (c0 >> 6) & 15, ks = c0 >> 10;
        const int o  = ot * 16 + (ln & 15);
        const int kb = ks * 32 + (ln >> 4) * 8;
        const float* p = w + (size_t)o * K + kb;
        float4 v0 = *(const float4*)p, v1 = *(const float4*)(p + 4);
        u16x8 h;
        h[0] = f2bf(v0.x); h[1] = f2bf(v0.y); h[2] = f2bf(v0.z); h[3] = f2bf(v0.w);
        h[4] = f2bf(v1.x); h[5] = f2bf(v1.y); h[6] = f2bf(v1.z); h[7] = f2bf(v1.w);
        *(u16x8*)&Wf[(size_t)c0 * 8] = h;
    }
}

// ================= main: 16 rows/block, 8 waves (512 thr), wave = K-eighth =================
// All oacc indices are compile-time constants (rule #20). Combine is a static
// 2-stage LDS tree; store fuses the 4-buffer sum + normalization.
constexpr int PP = 40;   // Ps row stride in ushorts

__global__ __launch_bounds__(512, 2)   // 2 blocks/CU: 16 waves/CU, VGPR cap 128
void rbf_main8(const ushort* __restrict__ Xh, const ushort* __restrict__ Xl,
               const ushort* __restrict__ Ch, const ushort* __restrict__ Cl,
               const ushort* __restrict__ Wf, const float* __restrict__ xs2,
               const float2* __restrict__ ecs, float* __restrict__ out, int N)
{
    __shared__ ushort Ps[8][16][PP];      // 10.2 KB, per-wave private
    __shared__ float  Acc[4][16][O + 4];  // 66.6 KB
    __shared__ float  Ls[8][16];          // 0.5 KB

    const int t = threadIdx.x, lane = t & 63, wv = t >> 6;   // wv 0..7
    const int l15 = lane & 15, l4 = lane >> 4;
    const int pan = blockIdx.x;

    // X fragments (frag-ordered -> base + lane*16B); same 16 rows for all waves
    s16x8 xh[4], xl[4];
    {
        const size_t base = ((size_t)pan * 4) * 64 + lane;
#pragma unroll
        for (int q = 0; q < 4; ++q) {
            xh[q] = *(const s16x8*)&Xh[(base + q * 64) * 8];
            xl[q] = *(const s16x8*)&Xl[(base + q * 64) * 8];
        }
    }
    const float xs2v = xs2[pan * 16 + l15];

    f32x4 oacc[16];
#pragma unroll
    for (int i = 0; i < 16; ++i) oacc[i] = (f32x4){0.f, 0.f, 0.f, 0.f};
    float Lp = 0.f;

    const int kw = wv * 64;   // wave's kernel base (K-eighth)

#pragma unroll
    for (int s = 0; s < 2; ++s) {
        const int kslab = (kw >> 5) + s;
        const ushort* wbase = &Wf[(((size_t)kslab * 16) * 64 + lane) * 8];

        // GEMM1 (swapped: A=C, B=X) + exp2, two 16-kernel tiles
#pragma unroll
        for (int bt = 0; bt < 2; ++bt) {
            const size_t kt16 = (size_t)(kw >> 4) + s * 2 + bt;
            s16x8 ch[4], cl[4];
#pragma unroll
            for (int q = 0; q < 4; ++q) {
                const size_t cc = ((kt16 * 4 + q) * 64 + lane) * 8;
                ch[q] = *(const s16x8*)&Ch[cc];
                cl[q] = *(const s16x8*)&Cl[cc];
            }
            f32x4 ghh = (f32x4){0.f,0.f,0.f,0.f};
            f32x4 ghl = (f32x4){0.f,0.f,0.f,0.f};
            f32x4 glh = (f32x4){0.f,0.f,0.f,0.f};
#pragma unroll
            for (int q = 0; q < 4; ++q) {
                ghh = __builtin_amdgcn_mfma_f32_16x16x32_bf16(ch[q], xh[q], ghh, 0, 0, 0);
                ghl = __builtin_amdgcn_mfma_f32_16x16x32_bf16(ch[q], xl[q], ghl, 0, 0, 0);
                glh = __builtin_amdgcn_mfma_f32_16x16x32_bf16(cl[q], xh[q], glh, 0, 0, 0);
            }
            f32x4 g = ghh + ghl + glh;

            const int kbase = kw + s * 32 + bt * 16 + l4 * 4;
            float4 e0 = *(const float4*)&ecs[kbase];
            float4 e1 = *(const float4*)&ecs[kbase + 2];
            float ph0 = exp2f(fmaf(e0.x, fmaf(-2.f, g[0], xs2v), e0.y));
            float ph1 = exp2f(fmaf(e0.z, fmaf(-2.f, g[1], xs2v), e0.w));
            float ph2 = exp2f(fmaf(e1.x, fmaf(-2.f, g[2], xs2v), e1.y));
            float ph3 = exp2f(fmaf(e1.z, fmaf(-2.f, g[3], xs2v), e1.w));
            Lp += (ph0 + ph1) + (ph2 + ph3);
            uint p0 = (uint)f2bf(ph0) | ((uint)f2bf(ph1) << 16);
            uint p1 = (uint)f2bf(ph2) | ((uint)f2bf(ph3) << 16);
            *(uint2*)&Ps[wv][l15][bt * 16 + l4 * 4] = make_uint2(p0, p1);
        }

        // wave-private transpose read (same-wave DS order, no barrier) + GEMM2
        s16x8 pa = *(const s16x8*)&Ps[wv][l15][l4 * 8];
#pragma unroll
        for (int ot = 0; ot < 16; ++ot) {
            s16x8 bfr = *(const s16x8*)&wbase[(size_t)ot * 64 * 8];
            oacc[ot] = __builtin_amdgcn_mfma_f32_16x16x32_bf16(pa, bfr, oacc[ot], 0, 0, 0);
        }
    }

    // per-wave row sums (over its 64 kernels)
    {
        float v = Lp;
        v += __shfl_xor(v, 16);
        v += __shfl_xor(v, 32);
        if (lane < 16) Ls[wv][lane] = v;
    }

    // ---- combine 8 wave partials: static 2-stage tree ----
    if (wv < 4) {
#pragma unroll
        for (int ot = 0; ot < 16; ++ot)
#pragma unroll
            for (int r = 0; r < 4; ++r)
                Acc[wv][l4 * 4 + r][ot * 16 + l15] = oacc[ot][r];
    }
    __syncthreads();
    if (wv >= 4) {
#pragma unroll
        for (int ot = 0; ot < 16; ++ot)
#pragma unroll
            for (int r = 0; r < 4; ++r)
                Acc[wv - 4][l4 * 4 + r][ot * 16 + l15] += oacc[ot][r];
    }
    __syncthreads();

    // ---- store: sum 4 buffers + normalize; 512 thr, each 8 floats of one row ----
    {
        const int n  = t >> 5;          // 0..15
        const int c8 = (t & 31) * 8;
        float inv = 1.0f / (Ls[0][n] + Ls[1][n] + Ls[2][n] + Ls[3][n] +
                            Ls[4][n] + Ls[5][n] + Ls[6][n] + Ls[7][n] + 1e-9f);
        float4 a0 = *(const float4*)&Acc[0][n][c8];
        float4 b0 = *(const float4*)&Acc[1][n][c8];
        float4 c0 = *(const float4*)&Acc[2][n][c8];
        float4 d0 = *(const float4*)&Acc[3][n][c8];
        float4 a1 = *(const float4*)&Acc[0][n][c8 + 4];
        float4 b1 = *(const float4*)&Acc[1][n][c8 + 4];
        float4 c1 = *(const float4*)&Acc[2][n][c8 + 4];
        float4 d1 = *(const float4*)&Acc[3][n][c8 + 4];
        float4 o0, o1;
        o0.x = ((a0.x + b0.x) + (c0.x + d0.x)) * inv;
        o0.y = ((a0.y + b0.y) + (c0.y + d0.y)) * inv;
        o0.z = ((a0.z + b0.z) + (c0.z + d0.z)) * inv;
        o0.w = ((a0.w + b0.w) + (c0.w + d0.w)) * inv;
        o1.x = ((a1.x + b1.x) + (c1.x + d1.x)) * inv;
        o1.y = ((a1.y + b1.y) + (c1.y + d1.y)) * inv;
        o1.z = ((a1.z + b1.z) + (c1.z + d1.z)) * inv;
        o1.w = ((a1.w + b1.w) + (c1.w + d1.w)) * inv;
        float* po = &out[(size_t)(pan * 16 + n) * O + c8];
        *(float4*)po = o0;
        *(float4*)(po + 4) = o1;
    }
}

// ================= fallback (round-4 kernel, known-pass, no ws) =================
__global__ __launch_bounds__(NT, 2)
void rbf_fb(const float* __restrict__ x, const float* __restrict__ cen,
            const float* __restrict__ ls, const float* __restrict__ w,
            float* __restrict__ out)
{
    __shared__ ushort Ps2[2][4][16][PP];
    __shared__ float  Acc2[2][16][O + 4];
    __shared__ float  Ls2[4][16];
    const int t = threadIdx.x, lane = t & 63, wv = t >> 6;
    const int l15 = lane & 15, l4 = lane >> 4;
    const int nb = blockIdx.x * 16;

    s16x8 xh[4], xl[4];
    float sx = 0.f;
    {
        const float* xr = x + (size_t)(nb + l15) * D;
#pragma unroll
        for (int q = 0; q < 4; ++q) {
            float4 v0 = *(const float4*)(xr + q * 32 + l4 * 8);
            float4 v1 = *(const float4*)(xr + q * 32 + l4 * 8 + 4);
            float f[8] = {v0.x, v0.y, v0.z, v0.w, v1.x, v1.y, v1.z, v1.w};
            s16x8 hh, lo;
#pragma unroll
            for (int j = 0; j < 8; ++j) {
                sx = fmaf(f[j], f[j], sx);
                ushort hb = f2bf(f[j]);
                hh[j] = (short)hb; lo[j] = (short)f2bf(f[j] - bf2f(hb));
            }
            xh[q] = hh; xl[q] = lo;
        }
    }
    sx += __shfl_xor(sx, 16); sx += __shfl_xor(sx, 32);
    float xs2v[4];
#pragma unroll
    for (int r = 0; r < 4; ++r) xs2v[r] = __shfl(sx, l4 * 4 + r);

    f32x4 oacc[16];
#pragma unroll
    for (int ot = 0; ot < 16; ++ot) oacc[ot] = (f32x4){0.f,0.f,0.f,0.f};
    float Lp[4] = {0.f,0.f,0.f,0.f};
    const int kq = wv * (K / 4);

#pragma unroll
    for (int s = 0; s < 4; ++s) {
        const int k0 = kq + s * 32;
#pragma unroll
        for (int bt = 0; bt < 2; ++bt) {
            const int kk = k0 + bt * 16 + l15;
            const float* cr = cen + (size_t)kk * D;
            s16x8 ch[4], cl[4];
            float sc = 0.f;
#pragma unroll
            for (int q = 0; q < 4; ++q) {
                float4 v0 = *(const float4*)(cr + q * 32 + l4 * 8);
                float4 v1 = *(const float4*)(cr + q * 32 + l4 * 8 + 4);
                float f[8] = {v0.x, v0.y, v0.z, v0.w, v1.x, v1.y, v1.z, v1.w};
                s16x8 hh, lo;
#pragma unroll
                for (int j = 0; j < 8; ++j) {
                    sc = fmaf(f[j], f[j], sc);
                    ushort hb = f2bf(f[j]);
                    hh[j] = (short)hb; lo[j] = (short)f2bf(f[j] - bf2f(hb));
                }
                ch[q] = hh; cl[q] = lo;
            }
            sc += __shfl_xor(sc, 16); sc += __shfl_xor(sc, 32);
            float es_ = __expf(2.0f * ls[kk]);
            f32x4 ghh={0,0,0,0}, ghl={0,0,0,0}, glh={0,0,0,0};
#pragma unroll
            for (int q = 0; q < 4; ++q) {
                ghh = __builtin_amdgcn_mfma_f32_16x16x32_bf16(xh[q], ch[q], ghh, 0,0,0);
                ghl = __builtin_amdgcn_mfma_f32_16x16x32_bf16(xh[q], cl[q], ghl, 0,0,0);
                glh = __builtin_amdgcn_mfma_f32_16x16x32_bf16(xl[q], ch[q], glh, 0,0,0);
            }
            f32x4 gg = ghh + ghl + glh;
#pragma unroll
            for (int r = 0; r < 4; ++r) {
                float r2 = xs2v[r] + sc - 2.0f * gg[r];
                float ph = __expf(-es_ * r2);
                Lp[r] += ph;
                Ps2[s & 1][wv][l4 * 4 + r][bt * 16 + l15] = f2bf(ph);
            }
        }
        s16x8 pa = *(const s16x8*)&Ps2[s & 1][wv][l15][l4 * 8];
#pragma unroll
        for (int ot = 0; ot < 16; ++ot) {
            const float* wr = w + (size_t)(ot * 16 + l15) * K + k0;
            float4 v0 = *(const float4*)(wr + l4 * 8);
            float4 v1 = *(const float4*)(wr + l4 * 8 + 4);
            s16x8 bb;
            bb[0]=(short)f2bf(v0.x); bb[1]=(short)f2bf(v0.y); bb[2]=(short)f2bf(v0.z); bb[3]=(short)f2bf(v0.w);
            bb[4]=(short)f2bf(v1.x); bb[5]=(short)f2bf(v1.y); bb[6]=(short)f2bf(v1.z); bb[7]=(short)f2bf(v1.w);
            oacc[ot] = __builtin_amdgcn_mfma_f32_16x16x32_bf16(pa, bb, oacc[ot], 0,0,0);
        }
    }
#pragma unroll
    for (int r = 0; r < 4; ++r) {
        float v = Lp[r];
        v += __shfl_xor(v, 1); v += __shfl_xor(v, 2);
        v += __shfl_xor(v, 4); v += __shfl_xor(v, 8);
        if (l15 == 0) Ls2[wv][l4 * 4 + r] = v;
    }
    if (wv < 2) {
#pragma unroll
        for (int ot = 0; ot < 16; ++ot)
#pragma unroll
            for (int r = 0; r < 4; ++r)
                Acc2[wv][l4 * 4 + r][ot * 16 + l15] = oacc[ot][r];
    }
    __syncthreads();
    if (wv >= 2) {
#pragma unroll
        for (int ot = 0; ot < 16; ++ot)
#pragma unroll
            for (int r = 0; r < 4; ++r)
                Acc2[wv - 2][l4 * 4 + r][ot * 16 + l15] += oacc[ot][r];
    }
    __syncthreads();
#pragma unroll
    for (int rr = 0; rr < 4; ++rr) {
        const int n = wv * 4 + rr;
        float inv = 1.0f / (Ls2[0][n] + Ls2[1][n] + Ls2[2][n] + Ls2[3][n] + 1e-9f);
        float4 a0 = *(const float4*)&Acc2[0][n][lane * 4];
        float4 a1 = *(const float4*)&Acc2[1][n][lane * 4];
        float4 o4;
        o4.x = (a0.x + a1.x) * inv; o4.y = (a0.y + a1.y) * inv;
        o4.z = (a0.z + a1.z) * inv; o4.w = (a0.w + a1.w) * inv;
        *(float4*)&out[(size_t)(nb + n) * O + lane * 4] = o4;
    }
}

extern "C" void kernel_launch(void* const* d_in, const int* in_sizes, int n_in,
                              void* d_out, int out_size, void* d_ws, size_t ws_size,
                              hipStream_t stream) {
    const float* x   = (const float*)d_in[0];  // N x 128
    const float* cen = (const float*)d_in[1];  // 512 x 128
    const float* ls  = (const float*)d_in[2];  // 512
    const float* w   = (const float*)d_in[3];  // 256 x 512
    float* out = (float*)d_out;                // N x 256
    const int N = in_sizes[0] / D;             // 8192

    size_t oXh = 0;
    size_t oXl = oXh + (size_t)N * D * 2;
    size_t oCh = oXl + (size_t)N * D * 2;
    size_t oCl = oCh + (size_t)K * D * 2;
    size_t oWf = oCl + (size_t)K * D * 2;
    size_t oxs = oWf + (size_t)O * K * 2;
    size_t oec = oxs + (size_t)N * 4;
    size_t need = oec + (size_t)K * 8;

    if (ws_size < need || (N % 16) != 0) {
        dim3 grid(N / 16), block(NT);
        hipLaunchKernelGGL(rbf_fb, grid, block, 0, stream, x, cen, ls, w, out);
        return;
    }

    char* ws = (char*)d_ws;
    ushort* Xh = (ushort*)(ws + oXh);
    ushort* Xl = (ushort*)(ws + oXl);
    ushort* Ch = (ushort*)(ws + oCh);
    ushort* Cl = (ushort*)(ws + oCl);
    ushort* Wf = (ushort*)(ws + oWf);
    float*  xs2 = (float*)(ws + oxs);
    float2* ecs = (float2*)(ws + oec);

    const int nxb = N / 16;                    // X panels
    const int ncb = K / 16;                    // C panels
    const int nwb = (O * K / 8) / NT;          // W blocks
    dim3 pgrid(nxb + ncb + nwb), pblock(NT);
    hipLaunchKernelGGL(rbf_prep, pgrid, pblock, 0, stream,
                       x, cen, ls, w, Xh, Xl, Ch, Cl, Wf, xs2, ecs, nxb, ncb);

    dim3 grid(N / 16), block(512);
    hipLaunchKernelGGL(rbf_main8, grid, block, 0, stream,
                       Xh, Xl, Ch, Cl, Wf, xs2, ecs, out, N);
}